// Round 8
// baseline (33.043 us; speedup 1.0000x reference)
//
#include <hip/hip_runtime.h>

// Input: (2, 1, 256, 256, 256) float32. x = inputs[:,0] -> (2,256,256,256).
// dd = (core - x[d+1]) * 256 ; dh = (core - x[h+1]) * 256 ; dw = (core - x[w+1]) * 256
// out = mean(|sqrt(dd^2+dh^2+dw^2) - 1|) over 2*255^3 core elements.
//
// Structure (round 7, 32.0us): two kernels, 1024 blocks, 8-plane d-chunks,
// 4-row register pencil per wave, XCD-chunked blockIdx swizzle.
// New: the h+4 boundary row (ch) is served by LDS cross-wave exchange --
// wave w+1's register row r0 IS wave w's ch. Parity double-buffered LDS,
// one barrier/iter; only wave 3 loads ch from global. Cuts 3 of 20 global
// loads per block-iter (test: vector-path-throughput vs L3-BW bound).

#define DVOL 256
#define PLANE (DVOL * DVOL)
#define CORE 255
#define DCH 8
#define NBLK 1024  // 2 b * 32 dchunks * 16 hgroups; 1024 % 8 == 0 -> bijective swizzle

__device__ __forceinline__ float sq(float v) { return v * v; }

__device__ __forceinline__ float row_term(const float4 c, const float4 h1,
                                          const float4 d1, int lane, bool valid) {
    const float nx = __shfl_down(c.x, 1, 64);  // lane+1's first element (all lanes participate)
    if (!valid) return 0.0f;
    float acc;
    float s;
    s = sq(c.x - d1.x) + sq(c.x - h1.x) + sq(c.x - c.y);
    acc = fabsf(fmaf(256.0f, sqrtf(s), -1.0f));
    s = sq(c.y - d1.y) + sq(c.y - h1.y) + sq(c.y - c.z);
    acc += fabsf(fmaf(256.0f, sqrtf(s), -1.0f));
    s = sq(c.z - d1.z) + sq(c.z - h1.z) + sq(c.z - c.w);
    acc += fabsf(fmaf(256.0f, sqrtf(s), -1.0f));
    if (lane != 63) {  // w = lane*4+3 = 255 is not core
        s = sq(c.w - d1.w) + sq(c.w - h1.w) + sq(c.w - nx);
        acc += fabsf(fmaf(256.0f, sqrtf(s), -1.0f));
    }
    return acc;
}

__global__ __launch_bounds__(256) void eik_partial(const float* __restrict__ x,
                                                   float* __restrict__ part) {
    __shared__ float4 xch[2][4][64];  // [parity][wave][lane]: wave's r0 (plane d, row h)

    const int tid  = threadIdx.x;
    const int lane = tid & 63;
    const int wave = tid >> 6;

    // XCD-chunked swizzle (hw: xcd = phys % 8) -> logical contiguous per XCD.
    const int blk = ((blockIdx.x & 7) << 7) + (blockIdx.x >> 3);

    const int b   = blk >> 9;               // batch
    const int dc  = (blk >> 4) & 31;        // d-chunk (8 planes)
    const int hg  = (blk & 15) * 4 + wave;  // h-group [0,64), 4 rows each
    const int h   = hg * 4;                 // first row: 0..252
    const int d0  = dc * DCH;
    const int dend = min(d0 + DCH, CORE);   // dc=31: 7 planes (same for all waves in block)
    const bool row3_valid = (h + 3 < CORE); // hg=63: row 255 not core
    const int ch_off = (h + 4 < DVOL) ? 4 * DVOL : 3 * DVOL;  // clamped, unused when invalid

    const float* base = x + (long long)b * (DVOL * PLANE)
                          + (long long)d0 * PLANE
                          + (long long)h * DVOL
                          + lane * 4;

    float4 r0 = *(const float4*)(base);
    float4 r1 = *(const float4*)(base + DVOL);
    float4 r2 = *(const float4*)(base + 2 * DVOL);
    float4 r3 = *(const float4*)(base + 3 * DVOL);

    float acc = 0.0f;
    int par = 0;
    for (int d = d0; d < dend; ++d) {
        xch[par][wave][lane] = r0;  // publish row h, plane d to wave-1
        __syncthreads();

        const float4 cd0 = *(const float4*)(base + PLANE);
        const float4 cd1 = *(const float4*)(base + PLANE + DVOL);
        const float4 cd2 = *(const float4*)(base + PLANE + 2 * DVOL);
        const float4 cd3 = *(const float4*)(base + PLANE + 3 * DVOL);
        float4 ch;
        if (wave < 3) {
            ch = xch[par][wave + 1][lane];             // row h+4, plane d (from LDS)
        } else {
            ch = *(const float4*)(base + ch_off);      // block boundary: global (L2 hit)
        }

        acc += row_term(r0, r1, cd0, lane, true);
        acc += row_term(r1, r2, cd1, lane, true);
        acc += row_term(r2, r3, cd2, lane, true);
        acc += row_term(r3, ch, cd3, lane, row3_valid);

        r0 = cd0; r1 = cd1; r2 = cd2; r3 = cd3;
        base += PLANE;
        par ^= 1;  // parity double-buffer: next iter writes other slot (no 2nd barrier)
    }

    // wave shuffle reduction
    #pragma unroll
    for (int off = 32; off > 0; off >>= 1)
        acc += __shfl_down(acc, off, 64);

    __shared__ float wsum[4];
    if (lane == 0) wsum[wave] = acc;
    __syncthreads();
    if (tid == 0)
        part[blk] = wsum[0] + wsum[1] + wsum[2] + wsum[3];
}

__global__ void eik_final(const float* __restrict__ part, float* __restrict__ out) {
    const int tid = threadIdx.x;
    double s = (double)part[tid] + (double)part[tid + 256]
             + (double)part[tid + 512] + (double)part[tid + 768];

    __shared__ double sm[256];
    sm[tid] = s;
    __syncthreads();
    #pragma unroll
    for (int off = 128; off > 0; off >>= 1) {
        if (tid < off) sm[tid] += sm[tid + off];
        __syncthreads();
    }
    if (tid == 0) {
        const double N = 2.0 * CORE * CORE * CORE;  // 33,162,750
        out[0] = (float)(sm[0] / N);
    }
}

extern "C" void kernel_launch(void* const* d_in, const int* in_sizes, int n_in,
                              void* d_out, int out_size, void* d_ws, size_t ws_size,
                              hipStream_t stream) {
    const float* x = (const float*)d_in[0];
    float* out = (float*)d_out;
    float* part = (float*)d_ws;  // 1024 floats = 4 KB

    eik_partial<<<NBLK, 256, 0, stream>>>(x, part);
    eik_final<<<1, 256, 0, stream>>>(part, out);
}